// Round 23
// baseline (120.943 us; speedup 1.0000x reference)
//
#include <hip/hip_runtime.h>
#include <cmath>

// Problem constants
#define NROWS 800        // BS*NQ
#define NCLS  81
#define MT    160        // targets
#define PPX   65536      // pixels per mask
#define SSPLIT 32        // K splits
#define CHUNK 2048       // PPX / SSPLIT
#define BK    128        // K (px) per pipeline step  -> 16 steps
#define STEPS (CHUNK / BK)   // 16
#define RPB   32         // rows per block
#define RB    25         // row blocks (25*32 = 800 exact)

// Workspace layout (bytes). t stored as fp8 e4m3 (binary -> exact).
#define OFF_TBF   0
#define SZ_TBF    (MT * PPX)                     // 10,485,760 (fp8, pre-swizzled)
#define OFF_CROSS (SZ_TBF)
#define OFF_SDOT  (OFF_CROSS + NROWS * MT * 4)
#define OFF_ROW   (OFF_SDOT + NROWS * MT * 4)
#define OFF_SSUM  (OFF_ROW + NROWS * 4)
#define OFF_TSUM  (OFF_SSUM + NROWS * 4)
#define OFF_ZEND  (OFF_TSUM + MT * 4)            // end of zeroed region

typedef __attribute__((ext_vector_type(4))) float f32x4;
typedef long i64;   // 8 fp8 = one MFMA operand half (2 VGPR)

typedef __attribute__((address_space(3))) char lds_char;
typedef const __attribute__((address_space(1))) char glob_char;

// ---------------------------------------------------------------------------
// Kernel 1: tgt_mask fp32 -> fp8 e4m3 (exact for 0/1), PRE-SWIZZLED: within
// each 128-px group, 16-px chunk c of row m lands at slot c^(m&7). + tsum.
// ---------------------------------------------------------------------------
__global__ __launch_bounds__(256) void prep_kernel(const float* __restrict__ tgt_mask,
                                                   char* __restrict__ ws) {
    int g = blockIdx.x * 256 + threadIdx.x;
    int m = g >> 13;            // 8192 8-px units per row
    int kc = g & 8191;
    const float4* src = (const float4*)(tgt_mask + (size_t)m * PPX + (kc << 3));
    float4 a = src[0], b = src[1];
    float part = a.x + a.y + a.z + a.w + b.x + b.y + b.z + b.w;

    unsigned w0 = __builtin_amdgcn_cvt_pk_fp8_f32(a.x, a.y, 0, false);
    w0 = __builtin_amdgcn_cvt_pk_fp8_f32(a.z, a.w, w0, true);
    unsigned w1 = __builtin_amdgcn_cvt_pk_fp8_f32(b.x, b.y, 0, false);
    w1 = __builtin_amdgcn_cvt_pk_fp8_f32(b.z, b.w, w1, true);

    int group = kc >> 4;                 // 128-px group
    int c = (kc >> 1) & 7;               // 16-px chunk within group
    int h = kc & 1;                      // 8-px half within chunk
    uint2 o; o.x = w0; o.y = w1;
    *(uint2*)(ws + OFF_TBF + (size_t)m * PPX + (size_t)group * 128
              + (size_t)(c ^ (m & 7)) * 16 + h * 8) = o;

    #pragma unroll
    for (int mk = 32; mk; mk >>= 1) part += __shfl_xor(part, mk);
    __shared__ float wsum[4];
    if ((threadIdx.x & 63) == 0) wsum[threadIdx.x >> 6] = part;
    __syncthreads();
    if (threadIdx.x == 0) {
        float tot = wsum[0] + wsum[1] + wsum[2] + wsum[3];
        atomicAdd((float*)(ws + OFF_TSUM) + m, tot);
    }
}

// ---------------------------------------------------------------------------
// Kernel 3: fused elementwise + dual GEMM (split-K), FP8, STAGE-AHEAD,
// + setprio around the MFMA cluster. (Best-measured family: 114 us total.)
// ---------------------------------------------------------------------------
struct XS4 { float4 a, b, c, d; };      // 16 consecutive px fp32 (64 B)

__device__ __forceinline__ void loadx(XS4& x, const float* xrow, int st) {
    const float* p = xrow + st * BK;
    x.a = *(const float4*)(p);
    x.b = *(const float4*)(p + 4);
    x.c = *(const float4*)(p + 8);
    x.d = *(const float4*)(p + 12);
}

// 4 px: sigmoid + softplus(log2-units) accumulate; pack x and s to fp8 words.
__device__ __forceinline__ void ew4(const float4 v, unsigned& wx, unsigned& ws_,
                                    float& slog2, float& sg_acc) {
    float s[4]; float vals[4] = {v.x, v.y, v.z, v.w};
    #pragma unroll
    for (int j = 0; j < 4; ++j) {
        float t = vals[j];
        float vl = fminf(t * 1.44269504089f, 126.f);
        float t2 = __builtin_amdgcn_exp2f(vl);               // e^t
        float d = 1.f + t2;
        float r = __builtin_amdgcn_rcpf(d);
        s[j] = t2 * r;                                       // sigmoid(t)
        slog2 += __builtin_amdgcn_logf(d);                   // log2(1+e^t)
        sg_acc += s[j];
    }
    wx = __builtin_amdgcn_cvt_pk_fp8_f32(vals[0], vals[1], 0, false);
    wx = __builtin_amdgcn_cvt_pk_fp8_f32(vals[2], vals[3], wx, true);
    ws_ = __builtin_amdgcn_cvt_pk_fp8_f32(s[0], s[1], 0, false);
    ws_ = __builtin_amdgcn_cvt_pk_fp8_f32(s[2], s[3], ws_, true);
}

__global__ __launch_bounds__(256) void main_kernel(const float* __restrict__ pred_masks,
                                                   char* __restrict__ ws) {
    __shared__ __align__(16) char lds_t[2][MT * BK];     // 2 x 20480 B (fp8)
    __shared__ __align__(16) char lds_x[2][RPB * BK];    // 2 x 4096 B
    __shared__ __align__(16) char lds_s[2][RPB * BK];    // 2 x 4096 B

    const int tid = threadIdx.x;
    const int w = tid >> 6, l = tid & 63;
    const int rb = blockIdx.x >> 5;      // 0..24
    const int s = blockIdx.x & 31;       // bid%8 = s%8 -> same-s blocks share XCD L2
    const int k_base = s * CHUNK;

    // ---- x coords: thread (row=tid>>3, c8=tid&7) reads 16 consecutive px
    const int row = tid >> 3;
    const int c8 = tid & 7;
    const int n_glob = rb * RPB + row;
    const float* xrow = pred_masks + (size_t)n_glob * PPX + k_base + c8 * 16;
    const int xoff = row * 128 + ((c8 ^ (row & 7)) * 16);

    const char* tbase = ws + OFF_TBF;

    // stage the 160x128 fp8 t-tile of step st into lds_t[buf]
    auto stage_t = [&](int buf, int st) {
        const size_t k0 = k_base + st * BK;
        #pragma unroll
        for (int i = 0; i < 5; ++i) {
            int rows_base = w * 40 + i * 8;
            const char* g = tbase + (size_t)(rows_base + (l >> 3)) * PPX
                          + k0 + (size_t)(l & 7) * 16;
            __builtin_amdgcn_global_load_lds((glob_char*)g,
                                             (lds_char*)(lds_t[buf] + rows_base * 128),
                                             16, 0, 0);
        }
    };

    const int wr = w & 1, wc = w >> 1;   // wave: 16-row half x 80-col half
    const int lrow = l & 15;
    const int inner8 = ((l >> 4) & 1) * 8;   // 8B half within 16B chunk
    const int cpair = (l >> 4) >> 1;         // chunk pair from lane group
    f32x4 accX[5], accS[5];
    #pragma unroll
    for (int i = 0; i < 5; ++i) { accX[i] = (f32x4)(0.f); accS[i] = (f32x4)(0.f); }
    float slog2 = 0.f, rs_sg = 0.f;

    XS4 XA, XB;     // XA: even tiles, XB: odd tiles

    // ---- prologue: stage tile0 -> buf0; ew tile0 -> buf0; x tiles 1,2 loaded
    stage_t(0, 0);
    __builtin_amdgcn_sched_barrier(0);
    loadx(XA, xrow, 0);
    loadx(XB, xrow, 1);
    {
        uint4 vx, vs;
        ew4(XA.a, vx.x, vs.x, slog2, rs_sg);
        ew4(XA.b, vx.y, vs.y, slog2, rs_sg);
        ew4(XA.c, vx.z, vs.z, slog2, rs_sg);
        ew4(XA.d, vx.w, vs.w, slog2, rs_sg);
        *(uint4*)(lds_x[0] + xoff) = vx;
        *(uint4*)(lds_s[0] + xoff) = vs;
    }
    loadx(XA, xrow, 2);
    // queue: [stage0 5][XA0 4][XB1 4][XA2 4]; ew already forced stage0+XA0
    // retired (in-order). vmcnt(8) = leave XB1+XA2 in flight; sound.
    __builtin_amdgcn_sched_barrier(0);
    asm volatile("s_waitcnt vmcnt(8) lgkmcnt(0)" ::: "memory");
    __builtin_amdgcn_sched_barrier(0);
    __builtin_amdgcn_s_barrier();
    __builtin_amdgcn_sched_barrier(0);

    #pragma unroll 1
    for (int it = 0; it < STEPS; it += 2) {
        #pragma unroll
        for (int half = 0; half < 2; ++half) {
            const int h = it + half;         // tile computed this step; p=half
            if (h + 1 < STEPS) {
                stage_t(half ^ 1, h + 1);
                __builtin_amdgcn_sched_barrier(0);
                // ew tile h+1 -> buf[half^1] (consume XB if h even, else XA)
                uint4 vx, vs;
                if (half == 0) {
                    ew4(XB.a, vx.x, vs.x, slog2, rs_sg);
                    ew4(XB.b, vx.y, vs.y, slog2, rs_sg);
                    ew4(XB.c, vx.z, vs.z, slog2, rs_sg);
                    ew4(XB.d, vx.w, vs.w, slog2, rs_sg);
                } else {
                    ew4(XA.a, vx.x, vs.x, slog2, rs_sg);
                    ew4(XA.b, vx.y, vs.y, slog2, rs_sg);
                    ew4(XA.c, vx.z, vs.z, slog2, rs_sg);
                    ew4(XA.d, vx.w, vs.w, slog2, rs_sg);
                }
                *(uint4*)(lds_x[half ^ 1] + xoff) = vx;
                *(uint4*)(lds_s[half ^ 1] + xoff) = vs;
                // refill the consumed set with tile h+3 (clamped; keeps the
                // VMEM queue shape uniform so vmcnt(4) stays sound)
                int tr = h + 3; if (tr >= STEPS) tr = STEPS - 1;
                if (half == 0) loadx(XB, xrow, tr);
                else           loadx(XA, xrow, tr);
                __builtin_amdgcn_sched_barrier(0);
            }

            // ---- MFMA tile h from buf[half], prioritized
            __builtin_amdgcn_s_setprio(1);
            #pragma unroll
            for (int ks = 0; ks < 4; ++ks) {
                const int arow = wr * 16 + lrow;
                const int ac = (2 * ks + cpair) ^ (arow & 7);
                i64 ax = *(const i64*)(lds_x[half] + arow * 128 + ac * 16 + inner8);
                i64 as_ = *(const i64*)(lds_s[half] + arow * 128 + ac * 16 + inner8);
                #pragma unroll
                for (int cf = 0; cf < 5; ++cf) {
                    const int mrow = (wc * 5 + cf) * 16 + lrow;
                    const int bc = (2 * ks + cpair) ^ (mrow & 7);
                    i64 bv = *(const i64*)(lds_t[half] + mrow * 128 + bc * 16 + inner8);
                    accX[cf] = __builtin_amdgcn_mfma_f32_16x16x32_fp8_fp8(ax, bv, accX[cf], 0, 0, 0);
                    accS[cf] = __builtin_amdgcn_mfma_f32_16x16x32_fp8_fp8(as_, bv, accS[cf], 0, 0, 0);
                }
            }
            __builtin_amdgcn_s_setprio(0);

            if (h + 1 < STEPS) {
                // one barrier per step: lgkm drains this step's ds reads +
                // next-tile ds_writes; vmcnt(4) retires stage(h+1) (issued a
                // full step of work ago), leaving the 4 x-refills in flight.
                asm volatile("s_waitcnt vmcnt(4) lgkmcnt(0)" ::: "memory");
                __builtin_amdgcn_sched_barrier(0);
                __builtin_amdgcn_s_barrier();
                __builtin_amdgcn_sched_barrier(0);
            }
        }
    }

    asm volatile("s_waitcnt vmcnt(0)" ::: "memory");

    // ---- row sums: reduce over the 8 threads sharing a row
    float rs_sp = slog2 * 0.69314718056f;
    rs_sp += __shfl_xor(rs_sp, 1); rs_sp += __shfl_xor(rs_sp, 2); rs_sp += __shfl_xor(rs_sp, 4);
    rs_sg += __shfl_xor(rs_sg, 1); rs_sg += __shfl_xor(rs_sg, 2); rs_sg += __shfl_xor(rs_sg, 4);
    float* acc_row = (float*)(ws + OFF_ROW);
    float* acc_ssum = (float*)(ws + OFF_SSUM);
    if ((tid & 7) == 0) {
        atomicAdd(acc_row + n_glob, rs_sp);
        atomicAdd(acc_ssum + n_glob, rs_sg);
    }

    // ---- split-K accumulate the C fragments
    float* acc_cross = (float*)(ws + OFF_CROSS);
    float* acc_sdot = (float*)(ws + OFF_SDOT);
    #pragma unroll
    for (int cf = 0; cf < 5; ++cf) {
        int mcol = (wc * 5 + cf) * 16 + lrow;
        #pragma unroll
        for (int i = 0; i < 4; ++i) {
            int nrow = rb * RPB + wr * 16 + (l >> 4) * 4 + i;
            atomicAdd(acc_cross + nrow * MT + mcol, accX[cf][i]);
            atomicAdd(acc_sdot + nrow * MT + mcol, accS[cf][i]);
        }
    }
}

// ---------------------------------------------------------------------------
// Kernel 4: fused softmax + combine. One block per row n (192 threads):
// 81-class softmax denominator computed in-block (LDS broadcast), then the
// 160 m-threads combine cls/mask/dice into out[n][m]. Removes the separate
// softmax kernel and the PROB buffer round-trip.
// ---------------------------------------------------------------------------
__global__ __launch_bounds__(192) void final_kernel(const float* __restrict__ logits,
                                                    const int* __restrict__ tgt_ids,
                                                    const char* __restrict__ ws,
                                                    float* __restrict__ out) {
    __shared__ float lcls[NCLS];
    const int n = blockIdx.x;
    const int t = threadIdx.x;

    if (t < NCLS) lcls[t] = logits[n * NCLS + t];
    __syncthreads();

    // all threads: max + denominator over the 81 classes (LDS broadcast reads)
    float mx = -INFINITY;
    #pragma unroll 1
    for (int c = 0; c < NCLS; ++c) mx = fmaxf(mx, lcls[c]);
    float den = 0.f;
    #pragma unroll 1
    for (int c = 0; c < NCLS; ++c) den += __expf(lcls[c] - mx);
    const float inv = 1.f / den;

    if (t < MT) {
        const int m = t;
        const int idx = n * MT + m;
        const float* acc_cross = (const float*)(ws + OFF_CROSS);
        const float* acc_sdot = (const float*)(ws + OFF_SDOT);
        const float* acc_row = (const float*)(ws + OFF_ROW);
        const float* acc_ssum = (const float*)(ws + OFF_SSUM);
        const float* tsum = (const float*)(ws + OFF_TSUM);

        float cls = -__expf(lcls[tgt_ids[m]] - mx) * inv;
        float cmask = (acc_row[n] - acc_cross[idx]) * (1.f / PPX);
        float cdice = 1.f - (2.f * acc_sdot[idx] + 1.f) / (acc_ssum[n] + tsum[m] + 1.f);
        out[idx] = cls + cmask + cdice;
    }
}

extern "C" void kernel_launch(void* const* d_in, const int* in_sizes, int n_in,
                              void* d_out, int out_size, void* d_ws, size_t ws_size,
                              hipStream_t stream) {
    const float* pred_logits = (const float*)d_in[0];
    const float* pred_masks  = (const float*)d_in[1];
    const int*   tgt_ids     = (const int*)d_in[2];
    const float* tgt_mask    = (const float*)d_in[3];
    char* ws = (char*)d_ws;

    (void)hipMemsetAsync(ws + OFF_CROSS, 0, OFF_ZEND - OFF_CROSS, stream);
    prep_kernel<<<5120, 256, 0, stream>>>(tgt_mask, ws);
    main_kernel<<<RB * SSPLIT, 256, 0, stream>>>(pred_masks, ws);
    final_kernel<<<NROWS, 192, 0, stream>>>(pred_logits, tgt_ids, ws, (float*)d_out);
}

// Round 24
// 113.258 us; speedup vs baseline: 1.0679x; 1.0679x over previous
//
#include <hip/hip_runtime.h>
#include <cmath>

// Problem constants
#define NROWS 800        // BS*NQ
#define NCLS  81
#define MT    160        // targets
#define PPX   65536      // pixels per mask
#define SSPLIT 32        // K splits
#define CHUNK 2048       // PPX / SSPLIT
#define BK    128        // K (px) per pipeline step  -> 16 steps
#define STEPS (CHUNK / BK)   // 16
#define RPB   32         // rows per block
#define RB    25         // row blocks (25*32 = 800 exact)

// Workspace layout (bytes). t stored as fp8 e4m3 (binary -> exact).
#define OFF_TBF   0
#define SZ_TBF    (MT * PPX)                     // 10,485,760 (fp8, pre-swizzled)
#define OFF_CROSS (SZ_TBF)
#define OFF_SDOT  (OFF_CROSS + NROWS * MT * 4)
#define OFF_ROW   (OFF_SDOT + NROWS * MT * 4)
#define OFF_SSUM  (OFF_ROW + NROWS * 4)
#define OFF_TSUM  (OFF_SSUM + NROWS * 4)
#define OFF_PROB  (OFF_TSUM + MT * 4)
#define OFF_END   (OFF_PROB + NROWS * NCLS * 4)

typedef __attribute__((ext_vector_type(4))) float f32x4;
typedef long i64;   // 8 fp8 = one MFMA operand half (2 VGPR)

typedef __attribute__((address_space(3))) char lds_char;
typedef const __attribute__((address_space(1))) char glob_char;

// ---------------------------------------------------------------------------
// Kernel 1: tgt_mask fp32 -> fp8 e4m3 (exact for 0/1), PRE-SWIZZLED: within
// each 128-px group, 16-px chunk c of row m lands at slot c^(m&7). + tsum.
// ---------------------------------------------------------------------------
__global__ __launch_bounds__(256) void prep_kernel(const float* __restrict__ tgt_mask,
                                                   char* __restrict__ ws) {
    int g = blockIdx.x * 256 + threadIdx.x;
    int m = g >> 13;            // 8192 8-px units per row
    int kc = g & 8191;
    const float4* src = (const float4*)(tgt_mask + (size_t)m * PPX + (kc << 3));
    float4 a = src[0], b = src[1];
    float part = a.x + a.y + a.z + a.w + b.x + b.y + b.z + b.w;

    unsigned w0 = __builtin_amdgcn_cvt_pk_fp8_f32(a.x, a.y, 0, false);
    w0 = __builtin_amdgcn_cvt_pk_fp8_f32(a.z, a.w, w0, true);
    unsigned w1 = __builtin_amdgcn_cvt_pk_fp8_f32(b.x, b.y, 0, false);
    w1 = __builtin_amdgcn_cvt_pk_fp8_f32(b.z, b.w, w1, true);

    int group = kc >> 4;                 // 128-px group
    int c = (kc >> 1) & 7;               // 16-px chunk within group
    int h = kc & 1;                      // 8-px half within chunk
    uint2 o; o.x = w0; o.y = w1;
    *(uint2*)(ws + OFF_TBF + (size_t)m * PPX + (size_t)group * 128
              + (size_t)(c ^ (m & 7)) * 16 + h * 8) = o;

    #pragma unroll
    for (int mk = 32; mk; mk >>= 1) part += __shfl_xor(part, mk);
    __shared__ float wsum[4];
    if ((threadIdx.x & 63) == 0) wsum[threadIdx.x >> 6] = part;
    __syncthreads();
    if (threadIdx.x == 0) {
        float tot = wsum[0] + wsum[1] + wsum[2] + wsum[3];
        atomicAdd((float*)(ws + OFF_TSUM) + m, tot);
    }
}

// ---------------------------------------------------------------------------
// Kernel 2: row softmax of pred_logits -> prob[800][81]
// ---------------------------------------------------------------------------
__global__ __launch_bounds__(64) void softmax_kernel(const float* __restrict__ logits,
                                                     float* __restrict__ prob) {
    int n = blockIdx.x;
    int l = threadIdx.x;
    const float* row = logits + n * NCLS;
    float v0 = row[l];
    float v1 = (l + 64 < NCLS) ? row[l + 64] : -INFINITY;
    float mx = fmaxf(v0, v1);
    #pragma unroll
    for (int mk = 32; mk; mk >>= 1) mx = fmaxf(mx, __shfl_xor(mx, mk));
    float e0 = __expf(v0 - mx);
    float e1 = (l + 64 < NCLS) ? __expf(v1 - mx) : 0.f;
    float s = e0 + e1;
    #pragma unroll
    for (int mk = 32; mk; mk >>= 1) s += __shfl_xor(s, mk);
    float inv = 1.f / s;
    prob[n * NCLS + l] = e0 * inv;
    if (l + 64 < NCLS) prob[n * NCLS + l + 64] = e1 * inv;
}

// ---------------------------------------------------------------------------
// Kernel 3: fused elementwise + dual GEMM (split-K), FP8, STAGE-AHEAD.
// Double-buffered t/x/s; step h: MFMA tile h from buf[p] while staging tile
// h+1 (glld) + ew-writing tile h+1 x/s into buf[p^1]. ONE barrier per step
// with combined s_waitcnt vmcnt(4) lgkmcnt(0). Best-measured: 114.0 us total.
// ---------------------------------------------------------------------------
struct XS4 { float4 a, b, c, d; };      // 16 consecutive px fp32 (64 B)

__device__ __forceinline__ void loadx(XS4& x, const float* xrow, int st) {
    const float* p = xrow + st * BK;
    x.a = *(const float4*)(p);
    x.b = *(const float4*)(p + 4);
    x.c = *(const float4*)(p + 8);
    x.d = *(const float4*)(p + 12);
}

// 4 px: sigmoid + softplus(log2-units) accumulate; pack x and s to fp8 words.
__device__ __forceinline__ void ew4(const float4 v, unsigned& wx, unsigned& ws_,
                                    float& slog2, float& sg_acc) {
    float s[4]; float vals[4] = {v.x, v.y, v.z, v.w};
    #pragma unroll
    for (int j = 0; j < 4; ++j) {
        float t = vals[j];
        float vl = fminf(t * 1.44269504089f, 126.f);
        float t2 = __builtin_amdgcn_exp2f(vl);               // e^t
        float d = 1.f + t2;
        float r = __builtin_amdgcn_rcpf(d);
        s[j] = t2 * r;                                       // sigmoid(t)
        slog2 += __builtin_amdgcn_logf(d);                   // log2(1+e^t)
        sg_acc += s[j];
    }
    wx = __builtin_amdgcn_cvt_pk_fp8_f32(vals[0], vals[1], 0, false);
    wx = __builtin_amdgcn_cvt_pk_fp8_f32(vals[2], vals[3], wx, true);
    ws_ = __builtin_amdgcn_cvt_pk_fp8_f32(s[0], s[1], 0, false);
    ws_ = __builtin_amdgcn_cvt_pk_fp8_f32(s[2], s[3], ws_, true);
}

__global__ __launch_bounds__(256) void main_kernel(const float* __restrict__ pred_masks,
                                                   char* __restrict__ ws) {
    __shared__ __align__(16) char lds_t[2][MT * BK];     // 2 x 20480 B (fp8)
    __shared__ __align__(16) char lds_x[2][RPB * BK];    // 2 x 4096 B
    __shared__ __align__(16) char lds_s[2][RPB * BK];    // 2 x 4096 B

    const int tid = threadIdx.x;
    const int w = tid >> 6, l = tid & 63;
    const int rb = blockIdx.x >> 5;      // 0..24
    const int s = blockIdx.x & 31;       // bid%8 = s%8 -> same-s blocks share XCD L2
    const int k_base = s * CHUNK;

    // ---- x coords: thread (row=tid>>3, c8=tid&7) reads 16 consecutive px
    const int row = tid >> 3;
    const int c8 = tid & 7;
    const int n_glob = rb * RPB + row;
    const float* xrow = pred_masks + (size_t)n_glob * PPX + k_base + c8 * 16;
    const int xoff = row * 128 + ((c8 ^ (row & 7)) * 16);

    const char* tbase = ws + OFF_TBF;

    // stage the 160x128 fp8 t-tile of step st into lds_t[buf]
    auto stage_t = [&](int buf, int st) {
        const size_t k0 = k_base + st * BK;
        #pragma unroll
        for (int i = 0; i < 5; ++i) {
            int rows_base = w * 40 + i * 8;
            const char* g = tbase + (size_t)(rows_base + (l >> 3)) * PPX
                          + k0 + (size_t)(l & 7) * 16;
            __builtin_amdgcn_global_load_lds((glob_char*)g,
                                             (lds_char*)(lds_t[buf] + rows_base * 128),
                                             16, 0, 0);
        }
    };

    const int wr = w & 1, wc = w >> 1;   // wave: 16-row half x 80-col half
    const int lrow = l & 15;
    const int inner8 = ((l >> 4) & 1) * 8;   // 8B half within 16B chunk
    const int cpair = (l >> 4) >> 1;         // chunk pair from lane group
    f32x4 accX[5], accS[5];
    #pragma unroll
    for (int i = 0; i < 5; ++i) { accX[i] = (f32x4)(0.f); accS[i] = (f32x4)(0.f); }
    float slog2 = 0.f, rs_sg = 0.f;

    XS4 XA, XB;     // XA: even tiles, XB: odd tiles

    // ---- prologue: stage tile0 -> buf0; ew tile0 -> buf0; x tiles 1,2 loaded
    stage_t(0, 0);
    __builtin_amdgcn_sched_barrier(0);
    loadx(XA, xrow, 0);
    loadx(XB, xrow, 1);
    {
        uint4 vx, vs;
        ew4(XA.a, vx.x, vs.x, slog2, rs_sg);
        ew4(XA.b, vx.y, vs.y, slog2, rs_sg);
        ew4(XA.c, vx.z, vs.z, slog2, rs_sg);
        ew4(XA.d, vx.w, vs.w, slog2, rs_sg);
        *(uint4*)(lds_x[0] + xoff) = vx;
        *(uint4*)(lds_s[0] + xoff) = vs;
    }
    loadx(XA, xrow, 2);
    // queue: [stage0 5][XA0 4][XB1 4][XA2 4]; ew already forced stage0+XA0
    // retired (in-order). vmcnt(8) = leave XB1+XA2 in flight; sound.
    __builtin_amdgcn_sched_barrier(0);
    asm volatile("s_waitcnt vmcnt(8) lgkmcnt(0)" ::: "memory");
    __builtin_amdgcn_sched_barrier(0);
    __builtin_amdgcn_s_barrier();
    __builtin_amdgcn_sched_barrier(0);

    #pragma unroll 1
    for (int it = 0; it < STEPS; it += 2) {
        #pragma unroll
        for (int half = 0; half < 2; ++half) {
            const int h = it + half;         // tile computed this step; p=half
            if (h + 1 < STEPS) {
                stage_t(half ^ 1, h + 1);
                __builtin_amdgcn_sched_barrier(0);
                // ew tile h+1 -> buf[half^1] (consume XB if h even, else XA)
                uint4 vx, vs;
                if (half == 0) {
                    ew4(XB.a, vx.x, vs.x, slog2, rs_sg);
                    ew4(XB.b, vx.y, vs.y, slog2, rs_sg);
                    ew4(XB.c, vx.z, vs.z, slog2, rs_sg);
                    ew4(XB.d, vx.w, vs.w, slog2, rs_sg);
                } else {
                    ew4(XA.a, vx.x, vs.x, slog2, rs_sg);
                    ew4(XA.b, vx.y, vs.y, slog2, rs_sg);
                    ew4(XA.c, vx.z, vs.z, slog2, rs_sg);
                    ew4(XA.d, vx.w, vs.w, slog2, rs_sg);
                }
                *(uint4*)(lds_x[half ^ 1] + xoff) = vx;
                *(uint4*)(lds_s[half ^ 1] + xoff) = vs;
                // refill the consumed set with tile h+3 (clamped; keeps the
                // VMEM queue shape uniform so vmcnt(4) stays sound)
                int tr = h + 3; if (tr >= STEPS) tr = STEPS - 1;
                if (half == 0) loadx(XB, xrow, tr);
                else           loadx(XA, xrow, tr);
                __builtin_amdgcn_sched_barrier(0);
            }

            // ---- MFMA tile h from buf[half]
            #pragma unroll
            for (int ks = 0; ks < 4; ++ks) {
                const int arow = wr * 16 + lrow;
                const int ac = (2 * ks + cpair) ^ (arow & 7);
                i64 ax = *(const i64*)(lds_x[half] + arow * 128 + ac * 16 + inner8);
                i64 as_ = *(const i64*)(lds_s[half] + arow * 128 + ac * 16 + inner8);
                #pragma unroll
                for (int cf = 0; cf < 5; ++cf) {
                    const int mrow = (wc * 5 + cf) * 16 + lrow;
                    const int bc = (2 * ks + cpair) ^ (mrow & 7);
                    i64 bv = *(const i64*)(lds_t[half] + mrow * 128 + bc * 16 + inner8);
                    accX[cf] = __builtin_amdgcn_mfma_f32_16x16x32_fp8_fp8(ax, bv, accX[cf], 0, 0, 0);
                    accS[cf] = __builtin_amdgcn_mfma_f32_16x16x32_fp8_fp8(as_, bv, accS[cf], 0, 0, 0);
                }
            }

            if (h + 1 < STEPS) {
                // one barrier per step: lgkm drains this step's ds reads +
                // next-tile ds_writes; vmcnt(4) retires stage(h+1) (issued a
                // full step of work ago), leaving the 4 x-refills in flight.
                asm volatile("s_waitcnt vmcnt(4) lgkmcnt(0)" ::: "memory");
                __builtin_amdgcn_sched_barrier(0);
                __builtin_amdgcn_s_barrier();
                __builtin_amdgcn_sched_barrier(0);
            }
        }
    }

    asm volatile("s_waitcnt vmcnt(0)" ::: "memory");

    // ---- row sums: reduce over the 8 threads sharing a row
    float rs_sp = slog2 * 0.69314718056f;
    rs_sp += __shfl_xor(rs_sp, 1); rs_sp += __shfl_xor(rs_sp, 2); rs_sp += __shfl_xor(rs_sp, 4);
    rs_sg += __shfl_xor(rs_sg, 1); rs_sg += __shfl_xor(rs_sg, 2); rs_sg += __shfl_xor(rs_sg, 4);
    float* acc_row = (float*)(ws + OFF_ROW);
    float* acc_ssum = (float*)(ws + OFF_SSUM);
    if ((tid & 7) == 0) {
        atomicAdd(acc_row + n_glob, rs_sp);
        atomicAdd(acc_ssum + n_glob, rs_sg);
    }

    // ---- split-K accumulate the C fragments
    float* acc_cross = (float*)(ws + OFF_CROSS);
    float* acc_sdot = (float*)(ws + OFF_SDOT);
    #pragma unroll
    for (int cf = 0; cf < 5; ++cf) {
        int mcol = (wc * 5 + cf) * 16 + lrow;
        #pragma unroll
        for (int i = 0; i < 4; ++i) {
            int nrow = rb * RPB + wr * 16 + (l >> 4) * 4 + i;
            atomicAdd(acc_cross + nrow * MT + mcol, accX[cf][i]);
            atomicAdd(acc_sdot + nrow * MT + mcol, accS[cf][i]);
        }
    }
}

// ---------------------------------------------------------------------------
// Kernel 4: combine into C[n][m]
// ---------------------------------------------------------------------------
__global__ __launch_bounds__(256) void final_kernel(const int* __restrict__ tgt_ids,
                                                    const char* __restrict__ ws,
                                                    float* __restrict__ out) {
    int idx = blockIdx.x * 256 + threadIdx.x;   // 0..127999
    int n = idx / MT;
    int m = idx - n * MT;
    const float* prob = (const float*)(ws + OFF_PROB);
    const float* acc_cross = (const float*)(ws + OFF_CROSS);
    const float* acc_sdot = (const float*)(ws + OFF_SDOT);
    const float* acc_row = (const float*)(ws + OFF_ROW);
    const float* acc_ssum = (const float*)(ws + OFF_SSUM);
    const float* tsum = (const float*)(ws + OFF_TSUM);

    float cls = -prob[n * NCLS + tgt_ids[m]];
    float cmask = (acc_row[n] - acc_cross[idx]) * (1.f / PPX);
    float cdice = 1.f - (2.f * acc_sdot[idx] + 1.f) / (acc_ssum[n] + tsum[m] + 1.f);
    out[idx] = cls + cmask + cdice;
}

extern "C" void kernel_launch(void* const* d_in, const int* in_sizes, int n_in,
                              void* d_out, int out_size, void* d_ws, size_t ws_size,
                              hipStream_t stream) {
    const float* pred_logits = (const float*)d_in[0];
    const float* pred_masks  = (const float*)d_in[1];
    const int*   tgt_ids     = (const int*)d_in[2];
    const float* tgt_mask    = (const float*)d_in[3];
    char* ws = (char*)d_ws;

    (void)hipMemsetAsync(ws + OFF_CROSS, 0, OFF_END - OFF_CROSS, stream);
    prep_kernel<<<5120, 256, 0, stream>>>(tgt_mask, ws);
    softmax_kernel<<<NROWS, 64, 0, stream>>>(pred_logits, (float*)(ws + OFF_PROB));
    main_kernel<<<RB * SSPLIT, 256, 0, stream>>>(pred_masks, ws);
    final_kernel<<<500, 256, 0, stream>>>(tgt_ids, ws, (float*)d_out);
}